// Round 6
// baseline (660.161 us; speedup 1.0000x reference)
//
#include <hip/hip_runtime.h>
#include <hip/hip_cooperative_groups.h>

namespace cg = cooperative_groups;

#define NN 100000
#define EE 500000
#define LDSW 136     // padded bf16 row stride in LDS
#define GEMM_NG 1563 // ceil(100000/16/4)
#define SCAN_G2 196  // ceil(2*NN/1024)

typedef __attribute__((ext_vector_type(8))) short v8s;
typedef __attribute__((ext_vector_type(4))) float v4f;

// ---------- bf16 helpers (RNE) ----------
__device__ __forceinline__ short f2b(float f) {
  unsigned u = __float_as_uint(f);
  unsigned r = (u + 0x7FFFu + ((u >> 16) & 1u)) >> 16;
  return (short)r;
}
__device__ __forceinline__ float b2f(short s) {
  return __uint_as_float(((unsigned)(unsigned short)s) << 16);
}

// ================= cooperative: CSR (zero+hist+scan) + weight prep =================
// 256 blocks x 256 threads, phases separated by grid.sync().
__global__ __launch_bounds__(256) void csr_prep_coop_k(
    const int* __restrict__ ei_a, const int* __restrict__ ei_b,
    int* __restrict__ deg, int* __restrict__ offs, int* __restrict__ cursor,
    int* __restrict__ bsums, const float* __restrict__ W_src,
    const float* __restrict__ W_dst, const float* __restrict__ W_edge,
    const float* __restrict__ att_src, const float* __restrict__ att_dst,
    const float* __restrict__ att_edge, short* __restrict__ Wt,
    short* __restrict__ foldB, float* __restrict__ Wea,
    float* __restrict__ WdaL1) {
  cg::grid_group grid = cg::this_grid();
  __shared__ int sd[256];
  int b = blockIdx.x, t = threadIdx.x;
  int gtid = b * 256 + t;
  const int GSZ = 256 * 256;

  // ---- ph0: zero deg; prep weights (blocks 0..194) ----
  for (int i = gtid; i < 2 * NN; i += GSZ) deg[i] = 0;
  if (b < 192) {
    int c = b >> 6, bb = b & 63;
    int pi = (c == 2) ? 3 : c;
    const float* W = W_src + pi * 16384;
    int idx = bb * 256 + t;
    int k = idx >> 7, n = idx & 127;
    Wt[c * 16384 + n * 128 + k] = f2b(W[idx]);
  } else if (b < 195) {
    int c = b - 192;
    int pi = (c == 2) ? 3 : c;
    int wd_pi = (c == 0) ? 1 : ((c == 1) ? 0 : 3);
    const float* W = W_src + pi * 16384;
    const float* as_ = att_src + pi * 128;
    const float* Wd = W_dst + wd_pi * 16384;
    const float* ad_ = att_dst + wd_pi * 128;
    const float* We = W_edge + pi * 2048;
    const float* ae_ = att_edge + pi * 128;
    short* fB = foldB + c * 2048;
    if (t < 128) {
#pragma unroll
      for (int h = 0; h < 4; ++h) {
        float s = 0.f;
        for (int cc = 0; cc < 32; ++cc)
          s += W[t * 128 + h * 32 + cc] * as_[h * 32 + cc];
        fB[t * 16 + h] = f2b(s);
      }
#pragma unroll
      for (int j = 8; j < 16; ++j) fB[t * 16 + j] = 0;
    } else {
      int k = t - 128;
      float o[4];
#pragma unroll
      for (int h = 0; h < 4; ++h) {
        float s = 0.f;
        for (int cc = 0; cc < 32; ++cc)
          s += Wd[k * 128 + h * 32 + cc] * ad_[h * 32 + cc];
        o[h] = s;
        fB[k * 16 + 4 + h] = f2b(s);
      }
      if (c == 2) ((float4*)WdaL1)[k] = make_float4(o[0], o[1], o[2], o[3]);
      if (k < 16) {
        float wv[4];
#pragma unroll
        for (int h = 0; h < 4; ++h) {
          float s = 0.f;
          for (int cc = 0; cc < 32; ++cc)
            s += We[k * 128 + h * 32 + cc] * ae_[h * 32 + cc];
          wv[h] = s;
        }
        ((float4*)(Wea + c * 64))[k] = make_float4(wv[0], wv[1], wv[2], wv[3]);
      }
    }
  }
  grid.sync();

  // ---- ph1: histogram ----
  for (int e = gtid; e < 2 * EE; e += GSZ) {
    int dp = (e < EE) ? ei_a[EE + e] : NN + ei_b[e];
    atomicAdd(&deg[dp], 1);
  }
  grid.sync();

  // ---- ph2: per-block local scan (blocks 0..195, 1024-elem chunks) ----
  if (b < SCAN_G2) {
    int idx = b * 1024 + t * 4;
    int v0 = (idx < 2 * NN) ? deg[idx] : 0;
    int v1 = (idx + 1 < 2 * NN) ? deg[idx + 1] : 0;
    int v2 = (idx + 2 < 2 * NN) ? deg[idx + 2] : 0;
    int v3 = (idx + 3 < 2 * NN) ? deg[idx + 3] : 0;
    int s = v0 + v1 + v2 + v3;
    sd[t] = s;
    __syncthreads();
    for (int off = 1; off < 256; off <<= 1) {
      int x = (t >= off) ? sd[t - off] : 0;
      __syncthreads();
      sd[t] += x;
      __syncthreads();
    }
    int excl = sd[t] - s;
    if (idx < 2 * NN) offs[idx] = excl;
    if (idx + 1 < 2 * NN) offs[idx + 1] = excl + v0;
    if (idx + 2 < 2 * NN) offs[idx + 2] = excl + v0 + v1;
    if (idx + 3 < 2 * NN) offs[idx + 3] = excl + v0 + v1 + v2;
    if (t == 255) bsums[b] = sd[255];
  }
  grid.sync();

  // ---- ph3: every block scans bsums in LDS, applies its base; init cursor ----
  {
    int v = (t < SCAN_G2) ? bsums[t] : 0;
    sd[t] = v;
    __syncthreads();
    for (int off = 1; off < 256; off <<= 1) {
      int x = (t >= off) ? sd[t - off] : 0;
      __syncthreads();
      sd[t] += x;
      __syncthreads();
    }
    if (b < SCAN_G2) {
      int base = (b == 0) ? 0 : sd[b - 1];
      int idx = b * 1024 + t * 4;
#pragma unroll
      for (int i = 0; i < 4; ++i) {
        int id = idx + i;
        if (id < 2 * NN) {
          int v2 = offs[id] + base;
          offs[id] = v2;
          cursor[id] = v2;
        }
      }
    }
    if (gtid == 0) offs[2 * NN] = 2 * EE;
  }
}

// ================= GEMM: hs=A@W (bf16), es=A@Was, ed=A@Wda =================
template <bool A_F32, bool STORE_ED>
__device__ __forceinline__ void gemm_body(int blk, const void* __restrict__ Ap,
                                          const short* __restrict__ Wt,
                                          const short* __restrict__ foldB16,
                                          short* __restrict__ hs,
                                          float* __restrict__ es,
                                          float* __restrict__ ed, int N,
                                          short* sW, short* sF, short* sC) {
  int t = threadIdx.x;
  {
    const int4* wp = (const int4*)Wt;
    for (int c = t; c < 2048; c += 256) {
      int row = c >> 4, col = c & 15;
      *(int4*)&sW[row * LDSW + col * 8] = wp[c];
    }
    ((int4*)sF)[t] = ((const int4*)foldB16)[t];
  }
  __syncthreads();
  int wid = t >> 6, lane = t & 63;
  long tile = (long)blk * 4 + wid;
  if (tile * 16 >= N) return;
  long row0 = tile * 16;
  int m = lane & 15, q = lane >> 4;
  v8s af[4];
  if (A_F32) {
    const float* arow = (const float*)Ap + (row0 + m) * 128 + q * 8;
#pragma unroll
    for (int kc = 0; kc < 4; ++kc) {
      float4 lo = *(const float4*)(arow + kc * 32);
      float4 hi = *(const float4*)(arow + kc * 32 + 4);
      v8s f;
      f[0] = f2b(lo.x); f[1] = f2b(lo.y); f[2] = f2b(lo.z); f[3] = f2b(lo.w);
      f[4] = f2b(hi.x); f[5] = f2b(hi.y); f[6] = f2b(hi.z); f[7] = f2b(hi.w);
      af[kc] = f;
    }
  } else {
    const short* arow = (const short*)Ap + (row0 + m) * 128 + q * 8;
#pragma unroll
    for (int kc = 0; kc < 4; ++kc) af[kc] = *(const v8s*)(arow + kc * 32);
  }
  v8s ff[4];
#pragma unroll
  for (int kc = 0; kc < 4; ++kc) {
    v8s f;
#pragma unroll
    for (int j = 0; j < 8; ++j) f[j] = sF[(kc * 32 + q * 8 + j) * 16 + m];
    ff[kc] = f;
  }
  v4f zero4 = {0.f, 0.f, 0.f, 0.f};
  v4f accf = zero4;
#pragma unroll
  for (int kc = 0; kc < 4; ++kc)
    accf = __builtin_amdgcn_mfma_f32_16x16x32_bf16(af[kc], ff[kc], accf, 0, 0, 0);
  v4f acc[8];
#pragma unroll
  for (int ct = 0; ct < 8; ++ct) {
    acc[ct] = zero4;
#pragma unroll
    for (int kc = 0; kc < 4; ++kc) {
      v8s bfr = *(const v8s*)&sW[(ct * 16 + m) * LDSW + kc * 32 + q * 8];
      acc[ct] =
          __builtin_amdgcn_mfma_f32_16x16x32_bf16(af[kc], bfr, acc[ct], 0, 0, 0);
    }
  }
#pragma unroll
  for (int r = 0; r < 4; ++r) {
    long row = row0 + q * 4 + r;
    if (m < 4)
      es[row * 4 + m] = accf[r];
    else if (STORE_ED && m < 8)
      ed[row * 4 + (m - 4)] = accf[r];
  }
  short* myC = sC + wid * 16 * LDSW;
#pragma unroll
  for (int ct = 0; ct < 8; ++ct)
#pragma unroll
    for (int r = 0; r < 4; ++r)
      myC[(q * 4 + r) * LDSW + ct * 16 + m] = f2b(acc[ct][r]);
  {
    int row = lane >> 2, part = lane & 3;
    short* dst = hs + (row0 + row) * 128 + part * 32;
#pragma unroll
    for (int i = 0; i < 4; ++i)
      *(int4*)(dst + i * 8) = *(int4*)&myC[row * LDSW + part * 32 + i * 8];
  }
}

__global__ __launch_bounds__(256) void gemm01_k(
    const float* __restrict__ xu, const float* __restrict__ xi,
    const short* __restrict__ Wt, const short* __restrict__ foldB,
    short* __restrict__ hsU, short* __restrict__ hsI, float* __restrict__ esU,
    float* __restrict__ esI, float* __restrict__ edC0,
    float* __restrict__ edC1) {
  __shared__ short sW[128 * LDSW];
  __shared__ short sF[128 * 16];
  __shared__ short sC[4 * 16 * LDSW];
  int half = blockIdx.x >= GEMM_NG;
  int blk = blockIdx.x - (half ? GEMM_NG : 0);
  gemm_body<true, true>(blk, half ? (const void*)xi : (const void*)xu,
                        Wt + half * 16384, foldB + half * 2048,
                        half ? hsI : hsU, half ? esI : esU,
                        half ? edC0 : edC1, NN, sW, sF, sC);
}

__global__ __launch_bounds__(256) void gemm2_k(const short* __restrict__ A,
                                               const short* __restrict__ Wt,
                                               const short* __restrict__ foldB,
                                               short* __restrict__ hs,
                                               float* __restrict__ es) {
  __shared__ short sW[128 * LDSW];
  __shared__ short sF[128 * 16];
  __shared__ short sC[4 * 16 * LDSW];
  gemm_body<false, false>(blockIdx.x, A, Wt + 2 * 16384, foldB + 2 * 2048, hs,
                          es, nullptr, NN, sW, sF, sC);
}

// ================= alpha: w4 = exp(leaky_relu(es[src]+ed[dst]+ea@Wea)) =================
__device__ __forceinline__ float4 alpha_w(int s, int d,
                                          const float* __restrict__ ea_e,
                                          const float* __restrict__ es,
                                          const float* __restrict__ ed,
                                          const float* __restrict__ WeaC) {
  float4 es4 = ((const float4*)es)[s];
  float4 ed4 = ((const float4*)ed)[d];
  float acc[4] = {es4.x + ed4.x, es4.y + ed4.y, es4.z + ed4.z, es4.w + ed4.w};
  const float4* ea4 = (const float4*)ea_e;
#pragma unroll
  for (int qq = 0; qq < 4; ++qq) {
    float4 a = ea4[qq];
    float av[4] = {a.x, a.y, a.z, a.w};
#pragma unroll
    for (int i = 0; i < 4; ++i) {
      float4 w = ((const float4*)WeaC)[qq * 4 + i];
      acc[0] += av[i] * w.x;
      acc[1] += av[i] * w.y;
      acc[2] += av[i] * w.z;
      acc[3] += av[i] * w.w;
    }
  }
  float4 r;
#pragma unroll
  for (int h = 0; h < 4; ++h) {
    float v = acc[h];
    v = (v >= 0.f) ? v : 0.2f * v;
    ((float*)&r)[h] = __expf(v);  // alphas O(1): safe without max-subtraction
  }
  return r;
}

// layer-0 both convs, fused with CSR permute (slot assignment)
__global__ __launch_bounds__(256) void alphaperm01_k(
    const int* __restrict__ ei_a, const int* __restrict__ ei_b,
    int* __restrict__ cursor, const float* __restrict__ ea_a,
    const float* __restrict__ ea_b, const float* __restrict__ esU,
    const float* __restrict__ esI, const float* __restrict__ edC0,
    const float* __restrict__ edC1, const float* __restrict__ Wea,
    int* __restrict__ ss2, int* __restrict__ rank2,
    float4* __restrict__ wbufF) {
  int e = blockIdx.x * 256 + threadIdx.x;
  if (e >= 2 * EE) return;
  bool h0 = e < EE;
  int el = h0 ? e : e - EE;
  const int* ei = h0 ? ei_a : ei_b;
  int s = ei[el], d = ei[EE + el];
  int slot = atomicAdd(&cursor[h0 ? d : NN + d], 1);
  ss2[slot] = s;
  rank2[e] = slot;
  const float* ea = h0 ? ea_a : ea_b;
  const float* es = h0 ? esU : esI;
  const float* ed = h0 ? edC0 : edC1;
  wbufF[slot] = alpha_w(s, d, ea + (long)el * 16, es, ed, Wea + (h0 ? 0 : 64));
}

__global__ __launch_bounds__(256) void alpha2_k(
    const int* __restrict__ ei_b, const int* __restrict__ rank2,
    const float* __restrict__ ea_b, const float* __restrict__ es2,
    const float* __restrict__ edL1, const float* __restrict__ Wea,
    float4* __restrict__ wbufF) {
  int e = blockIdx.x * 256 + threadIdx.x;
  if (e >= EE) return;
  int s = ei_b[e], d = ei_b[EE + e];
  wbufF[rank2[EE + e]] =
      alpha_w(s, d, ea_b + (long)e * 16, es2, edL1, Wea + 128);
}

// ================= gather: weighted sum + bias + LN + ReLU =================
// 64 lanes per dst node; two 32-lane subgroups process even/odd edges (2x MLP);
// within a subgroup lane j owns channels 4j..4j+3, head h=j>>3.
__device__ __forceinline__ void gather_core(
    int rs, int re, int sg, int j, int h, const int* __restrict__ ss,
    const short* __restrict__ hs, const float* __restrict__ wbufF,
    const float* __restrict__ bias, const float* __restrict__ gamma,
    const float* __restrict__ beta, float* y) {
  float den = 0.f, a0 = 0.f, a1 = 0.f, a2 = 0.f, a3 = 0.f;
  for (int k = rs + sg; k < re; k += 2) {
    int s = ss[k];
    float w = wbufF[(long)k * 4 + h];
    unsigned long long pp =
        *(const unsigned long long*)(hs + (long)s * 128 + j * 4);
    float v0 = b2f((short)(pp & 0xFFFF));
    float v1 = b2f((short)((pp >> 16) & 0xFFFF));
    float v2 = b2f((short)((pp >> 32) & 0xFFFF));
    float v3 = b2f((short)(pp >> 48));
    den += w;
    a0 += w * v0;
    a1 += w * v1;
    a2 += w * v2;
    a3 += w * v3;
  }
  // combine the two subgroups
  den += __shfl_xor(den, 32);
  a0 += __shfl_xor(a0, 32);
  a1 += __shfl_xor(a1, 32);
  a2 += __shfl_xor(a2, 32);
  a3 += __shfl_xor(a3, 32);
  float inv = 1.f / (den + 1e-16f);
  float4 b4 = ((const float4*)bias)[j];
  float o0 = a0 * inv + b4.x, o1 = a1 * inv + b4.y;
  float o2 = a2 * inv + b4.z, o3 = a3 * inv + b4.w;
  float s1 = o0 + o1 + o2 + o3;
  float s2 = o0 * o0 + o1 * o1 + o2 * o2 + o3 * o3;
#pragma unroll
  for (int mm = 1; mm <= 16; mm <<= 1) {
    s1 += __shfl_xor(s1, mm);
    s2 += __shfl_xor(s2, mm);
  }
  float mu = s1 * (1.f / 128.f);
  float var = s2 * (1.f / 128.f) - mu * mu;
  float rstd = rsqrtf(var + 1e-5f);
  float4 g4 = ((const float4*)gamma)[j];
  float4 be4 = ((const float4*)beta)[j];
  y[0] = fmaxf((o0 - mu) * rstd * g4.x + be4.x, 0.f);
  y[1] = fmaxf((o1 - mu) * rstd * g4.y + be4.y, 0.f);
  y[2] = fmaxf((o2 - mu) * rstd * g4.z + be4.z, 0.f);
  y[3] = fmaxf((o3 - mu) * rstd * g4.w + be4.w, 0.f);
}

__global__ __launch_bounds__(256) void gather01_k(
    const int* __restrict__ offs2, const int* __restrict__ ss2,
    const short* __restrict__ hsU, const short* __restrict__ hsI,
    const float* __restrict__ wbufF, const float* __restrict__ bias,
    const float* __restrict__ ln_g, const float* __restrict__ ln_b,
    short* __restrict__ bufXI, short* __restrict__ bufXU,
    const float* __restrict__ WdaL1, float* __restrict__ edL1) {
  int t = threadIdx.x;
  int wid = t >> 6, lane = t & 63;
  int sg = lane >> 5, j = lane & 31, h = j >> 3;
  int g = blockIdx.x * 4 + wid;
  if (g >= 2 * NN) return;
  bool item = g < NN;
  float y[4];
  gather_core(offs2[g], offs2[g + 1], sg, j, h, ss2, item ? hsU : hsI, wbufF,
              bias + (item ? 0 : 128), ln_g + (item ? 128 : 0),
              ln_b + (item ? 128 : 0), y);
  long n = item ? g : g - NN;
  if (sg == 0) {
    unsigned long long p =
        (unsigned long long)(unsigned short)f2b(y[0]) |
        ((unsigned long long)(unsigned short)f2b(y[1]) << 16) |
        ((unsigned long long)(unsigned short)f2b(y[2]) << 32) |
        ((unsigned long long)(unsigned short)f2b(y[3]) << 48);
    ((unsigned long long*)(item ? bufXI : bufXU))[n * 32 + j] = p;
  }
  if (!item) {  // fold next layer's ed = y @ WdaL1 (both halves hold full y)
    float e0 = 0.f, e1 = 0.f, e2 = 0.f, e3 = 0.f;
#pragma unroll
    for (int r = 0; r < 4; ++r) {
      float4 wr = ((const float4*)WdaL1)[j * 4 + r];
      e0 += y[r] * wr.x;
      e1 += y[r] * wr.y;
      e2 += y[r] * wr.z;
      e3 += y[r] * wr.w;
    }
#pragma unroll
    for (int mm = 1; mm <= 16; mm <<= 1) {
      e0 += __shfl_xor(e0, mm);
      e1 += __shfl_xor(e1, mm);
      e2 += __shfl_xor(e2, mm);
      e3 += __shfl_xor(e3, mm);
    }
    if (lane == 0) ((float4*)edL1)[n] = make_float4(e0, e1, e2, e3);
  }
}

__global__ __launch_bounds__(256) void gather2_k(
    const int* __restrict__ offs, const int* __restrict__ ss2,
    const short* __restrict__ hs2, const float* __restrict__ wbufF,
    const float* __restrict__ bias, const float* __restrict__ ln_g,
    const float* __restrict__ ln_b, float* __restrict__ out) {
  int t = threadIdx.x;
  int wid = t >> 6, lane = t & 63;
  int sg = lane >> 5, j = lane & 31, h = j >> 3;
  int n = blockIdx.x * 4 + wid;
  if (n >= NN) return;
  float y[4];
  gather_core(offs[n], offs[n + 1], sg, j, h, ss2, hs2, wbufF, bias, ln_g,
              ln_b, y);
  if (sg == 0)
    ((float4*)out)[(long)n * 32 + j] = make_float4(y[0], y[1], y[2], y[3]);
}

extern "C" void kernel_launch(void* const* d_in, const int* in_sizes, int n_in,
                              void* d_out, int out_size, void* d_ws,
                              size_t ws_size, hipStream_t stream) {
  const float* x_user = (const float*)d_in[0];
  const float* x_item = (const float*)d_in[1];
  const int* ei_u2i = (const int*)d_in[2];
  const int* ei_i2u = (const int*)d_in[3];
  const float* ea_u2i = (const float*)d_in[4];
  const float* ea_i2u = (const float*)d_in[5];
  const float* W_src = (const float*)d_in[6];
  const float* W_dst = (const float*)d_in[7];
  const float* W_edge = (const float*)d_in[8];
  const float* att_src = (const float*)d_in[9];
  const float* att_dst = (const float*)d_in[10];
  const float* att_edge = (const float*)d_in[11];
  const float* bias = (const float*)d_in[12];
  const float* ln_g = (const float*)d_in[13];
  const float* ln_b = (const float*)d_in[14];

  char* w = (char*)d_ws;
  auto alloc = [&](size_t bytes) {
    void* p = w;
    w += (bytes + 255) & ~(size_t)255;
    return p;
  };
  const size_t NBH = (size_t)NN * 128 * sizeof(short);
  short* hsU = (short*)alloc(NBH);
  short* hsI = (short*)alloc(NBH);
  short* hs2 = (short*)alloc(NBH);
  short* bufXI = (short*)alloc(NBH);
  short* bufXU = (short*)alloc(NBH);
  float* esU = (float*)alloc((size_t)NN * 4 * sizeof(float));
  float* esI = (float*)alloc((size_t)NN * 4 * sizeof(float));
  float* es2 = (float*)alloc((size_t)NN * 4 * sizeof(float));
  float* edC0 = (float*)alloc((size_t)NN * 4 * sizeof(float));
  float* edC1 = (float*)alloc((size_t)NN * 4 * sizeof(float));
  float* edL1 = (float*)alloc((size_t)NN * 4 * sizeof(float));
  float4* wbufF = (float4*)alloc((size_t)2 * EE * sizeof(float4));
  short* Wt = (short*)alloc(3 * 16384 * sizeof(short));
  short* foldB = (short*)alloc(3 * 2048 * sizeof(short));
  float* Wea = (float*)alloc(3 * 64 * sizeof(float));
  float* WdaL1 = (float*)alloc(128 * 4 * sizeof(float));
  int* deg2 = (int*)alloc((size_t)2 * NN * sizeof(int));
  int* cursor2 = (int*)alloc((size_t)2 * NN * sizeof(int));
  int* bsums = (int*)alloc(1024);
  int* offs2 = (int*)alloc((size_t)(2 * NN + 8) * sizeof(int));
  int* ss2 = (int*)alloc((size_t)2 * EE * sizeof(int));
  int* rank2 = (int*)alloc((size_t)2 * EE * sizeof(int));

  const int E2G = (2 * EE + 255) / 256;

  // ---- 1) cooperative CSR (zero+hist+scan) + weight prep ----
  {
    const int* p_eia = ei_u2i;
    const int* p_eib = ei_i2u;
    int* p_deg = deg2;
    int* p_offs = offs2;
    int* p_cur = cursor2;
    int* p_bs = bsums;
    const float* p_ws = W_src;
    const float* p_wd = W_dst;
    const float* p_we = W_edge;
    const float* p_as = att_src;
    const float* p_ad = att_dst;
    const float* p_ae = att_edge;
    short* p_Wt = Wt;
    short* p_fB = foldB;
    float* p_Wea = Wea;
    float* p_WdaL1 = WdaL1;
    void* args[] = {&p_eia, &p_eib, &p_deg, &p_offs, &p_cur, &p_bs,
                    &p_ws,  &p_wd,  &p_we,  &p_as,   &p_ad,  &p_ae,
                    &p_Wt,  &p_fB,  &p_Wea, &p_WdaL1};
    hipLaunchCooperativeKernel((const void*)csr_prep_coop_k, dim3(256),
                               dim3(256), args, 0, stream);
  }

  // ---- 2) layer-0 GEMMs (both convs; es/ed folds fused) ----
  gemm01_k<<<2 * GEMM_NG, 256, 0, stream>>>(x_user, x_item, Wt, foldB, hsU,
                                            hsI, esU, esI, edC0, edC1);
  // ---- 3) alpha + CSR permute fused ----
  alphaperm01_k<<<E2G, 256, 0, stream>>>(ei_u2i, ei_i2u, cursor2, ea_u2i,
                                         ea_i2u, esU, esI, edC0, edC1, Wea,
                                         ss2, rank2, wbufF);
  // ---- 4) layer-0 gathers (both convs) + LN/ReLU + layer-1 ed fold ----
  gather01_k<<<(2 * NN + 3) / 4, 256, 0, stream>>>(
      offs2, ss2, hsU, hsI, (const float*)wbufF, bias, ln_g, ln_b, bufXI,
      bufXU, WdaL1, edL1);

  // ---- 5-7) layer 1 (user path only; item path dead) ----
  gemm2_k<<<GEMM_NG, 256, 0, stream>>>(bufXI, Wt, foldB, hs2, es2);
  alpha2_k<<<(EE + 255) / 256, 256, 0, stream>>>(ei_i2u, rank2, ea_i2u, es2,
                                                 edL1, Wea, wbufF);
  gather2_k<<<(NN + 3) / 4, 256, 0, stream>>>(
      offs2 + NN, ss2, hs2, (const float*)wbufF, bias + 3 * 128,
      ln_g + 2 * 128, ln_b + 2 * 128, (float*)d_out);
}